// Round 1
// baseline (735.191 us; speedup 1.0000x reference)
//
#include <hip/hip_runtime.h>
#include <cmath>

constexpr int N = 131072;     // nodes
constexpr int E = 4194304;    // edges (without self-loops)
constexpr int F = 16;         // hidden width H1

// ---- degree: self-loop init + per-edge atomic increment --------------------
__global__ void k_deg_init(float* __restrict__ deg) {
    int i = blockIdx.x * blockDim.x + threadIdx.x;
    if (i < N) deg[i] = 1.0f;   // self-loop contributes 1 to every node
}

__global__ void k_deg_edges(const int* __restrict__ dst, float* deg) {
    int e = blockIdx.x * blockDim.x + threadIdx.x;
    if (e < E) atomicAdd(&deg[dst[e]], 1.0f);
}

// ---- layer-1 node pass: dinv, h1 = x@W1, seed a1 with self-loop term -------
__global__ void k_node1(const float* __restrict__ x,
                        const float* __restrict__ W1,
                        float* deg /* in: deg, out: dinv (in place) */,
                        float* __restrict__ h1,
                        float* __restrict__ a1) {
    int i = blockIdx.x * blockDim.x + threadIdx.x;
    if (i >= N) return;
    float di = rsqrtf(deg[i]);
    deg[i] = di;                       // array now holds dinv
    float x0 = x[2 * i + 0];
    float x1 = x[2 * i + 1];
    float sw = di * di;                // self-loop norm = dinv[i]*dinv[i]
#pragma unroll
    for (int f = 0; f < F; ++f) {
        float h = fmaf(x0, W1[f], x1 * W1[F + f]);
        h1[(size_t)i * F + f] = h;
        a1[(size_t)i * F + f] = h * sw;
    }
}

// ---- layer-1 edge aggregation: 16 lanes per edge ---------------------------
__global__ void k_agg1(const int* __restrict__ src,
                       const int* __restrict__ dst,
                       const float* __restrict__ dinv,
                       const float* __restrict__ h1,
                       float* a1) {
    int tid = blockIdx.x * blockDim.x + threadIdx.x;  // < 64M, fits int
    int e = tid >> 4;
    int f = tid & 15;
    if (e >= E) return;
    int s = src[e];
    int d = dst[e];
    float nrm = dinv[s] * dinv[d];
    atomicAdd(&a1[(size_t)d * F + f], h1[(size_t)s * F + f] * nrm);
}

// ---- layer-2 node pass: relu(a1+b1)@W2 -> h2; seed acc2 with self-loop -----
__global__ void k_node2(const float* __restrict__ a1,
                        const float* __restrict__ b1,
                        const float* __restrict__ W2,
                        const float* __restrict__ dinv,
                        float* __restrict__ h2,
                        float* __restrict__ acc2) {
    int i = blockIdx.x * blockDim.x + threadIdx.x;
    if (i >= N) return;
    float acc = 0.0f;
#pragma unroll
    for (int f = 0; f < F; ++f) {
        float v = a1[(size_t)i * F + f] + b1[f];
        acc = fmaf(fmaxf(v, 0.0f), W2[f], acc);
    }
    float di = dinv[i];
    h2[i] = acc;
    acc2[i] = acc * di * di;           // self-loop contribution
}

// ---- layer-2 edge aggregation: one atomic per edge -------------------------
__global__ void k_agg2(const int* __restrict__ src,
                       const int* __restrict__ dst,
                       const float* __restrict__ dinv,
                       const float* __restrict__ h2,
                       float* acc2) {
    int e = blockIdx.x * blockDim.x + threadIdx.x;
    if (e >= E) return;
    int s = src[e];
    int d = dst[e];
    atomicAdd(&acc2[d], h2[s] * dinv[s] * dinv[d]);
}

// ---- sigmoid per node ------------------------------------------------------
__global__ void k_score(const float* __restrict__ b2, float* acc2) {
    int i = blockIdx.x * blockDim.x + threadIdx.x;
    if (i >= N) return;
    float v = acc2[i] + b2[0];
    acc2[i] = 1.0f / (1.0f + expf(-v));   // array now holds scores
}

// ---- gather per original edge: out[e] = scores[src[e]] ---------------------
__global__ void k_out(const int* __restrict__ src,
                      const float* __restrict__ scores,
                      float* __restrict__ out) {
    int e = blockIdx.x * blockDim.x + threadIdx.x;
    if (e >= E) return;
    out[e] = scores[src[e]];
}

extern "C" void kernel_launch(void* const* d_in, const int* in_sizes, int n_in,
                              void* d_out, int out_size, void* d_ws, size_t ws_size,
                              hipStream_t stream) {
    const float* x  = (const float*)d_in[0];   // [N,2]
    const float* W1 = (const float*)d_in[1];   // [2,16] row-major
    const float* b1 = (const float*)d_in[2];   // [16]
    const float* W2 = (const float*)d_in[3];   // [16,1]
    const float* b2 = (const float*)d_in[4];   // [1]
    const int*   ei = (const int*)d_in[5];     // [2,E]
    const int* src = ei;
    const int* dst = ei + E;

    float* ws   = (float*)d_ws;
    float* deg  = ws;                          // [N] -> becomes dinv
    float* h1   = deg + N;                     // [N*F]
    float* a1   = h1 + (size_t)N * F;          // [N*F]
    float* h2   = a1 + (size_t)N * F;          // [N]
    float* acc2 = h2 + N;                      // [N] -> becomes scores
    float* out  = (float*)d_out;               // [E]

    dim3 blk(256);
    k_deg_init<<<N / 256, blk, 0, stream>>>(deg);
    k_deg_edges<<<E / 256, blk, 0, stream>>>(dst, deg);
    k_node1<<<N / 256, blk, 0, stream>>>(x, W1, deg, h1, a1);
    k_agg1<<<(E / 256) * 16, blk, 0, stream>>>(src, dst, deg, h1, a1);
    k_node2<<<N / 256, blk, 0, stream>>>(a1, b1, W2, deg, h2, acc2);
    k_agg2<<<E / 256, blk, 0, stream>>>(src, dst, deg, h2, acc2);
    k_score<<<N / 256, blk, 0, stream>>>(b2, acc2);
    k_out<<<E / 256, blk, 0, stream>>>(src, acc2, out);
}

// Round 2
// 720.239 us; speedup vs baseline: 1.0208x; 1.0208x over previous
//
#include <hip/hip_runtime.h>
#include <cmath>

constexpr int N = 131072;     // nodes
constexpr int E = 4194304;    // edges (without self-loops)
constexpr int F = 16;         // hidden width H1

// ---- degree: self-loop init + per-edge atomic increment --------------------
__global__ void k_deg_init(float* __restrict__ deg) {
    int i = blockIdx.x * blockDim.x + threadIdx.x;
    if (i < N) deg[i] = 1.0f;   // self-loop contributes 1 to every node
}

__global__ void k_deg_edges(const int* __restrict__ dst, float* deg) {
    int e = blockIdx.x * blockDim.x + threadIdx.x;
    if (e < E) atomicAdd(&deg[dst[e]], 1.0f);
}

// ---- dinv + seed ax with self-loop contribution (2 floats/node) ------------
// ax[i] = segsum over edges of x[src]*norm, seeded with x[i]*dinv[i]^2
__global__ void k_dinv_seed(const float* __restrict__ x,
                            float* deg /* in: deg, out: dinv in place */,
                            float* __restrict__ ax) {
    int i = blockIdx.x * blockDim.x + threadIdx.x;
    if (i >= N) return;
    float di = rsqrtf(deg[i]);
    deg[i] = di;                 // array now holds dinv
    float sw = di * di;          // self-loop norm
    ax[2 * i + 0] = x[2 * i + 0] * sw;
    ax[2 * i + 1] = x[2 * i + 1] * sw;
}

// ---- layer-1 edge aggregation on RAW features: 2 lanes per edge ------------
// Linearity: segsum(norm * (x@W1)[src]) == (segsum(norm * x[src])) @ W1
__global__ void k_aggx(const int* __restrict__ src,
                       const int* __restrict__ dst,
                       const float* __restrict__ dinv,
                       const float* __restrict__ x,
                       float* ax) {
    int tid = blockIdx.x * blockDim.x + threadIdx.x;  // < 8M
    int e = tid >> 1;
    int f = tid & 1;
    if (e >= E) return;
    int s = src[e];
    int d = dst[e];
    float nrm = dinv[s] * dinv[d];
    atomicAdd(&ax[2 * d + f], x[2 * s + f] * nrm);
}

// ---- node pass: h1 = ax@W1 + b1, relu, dot W2 -> h2; seed acc2 -------------
__global__ void k_node2(const float* __restrict__ ax,
                        const float* __restrict__ W1,
                        const float* __restrict__ b1,
                        const float* __restrict__ W2,
                        const float* __restrict__ dinv,
                        float* __restrict__ h2,
                        float* __restrict__ acc2) {
    int i = blockIdx.x * blockDim.x + threadIdx.x;
    if (i >= N) return;
    float a0 = ax[2 * i + 0];
    float a1 = ax[2 * i + 1];
    float acc = 0.0f;
#pragma unroll
    for (int f = 0; f < F; ++f) {
        float v = fmaf(a0, W1[f], fmaf(a1, W1[F + f], b1[f]));
        acc = fmaf(fmaxf(v, 0.0f), W2[f], acc);
    }
    float di = dinv[i];
    h2[i] = acc;
    acc2[i] = acc * di * di;     // self-loop contribution
}

// ---- layer-2 edge aggregation: one atomic per edge -------------------------
__global__ void k_agg2(const int* __restrict__ src,
                       const int* __restrict__ dst,
                       const float* __restrict__ dinv,
                       const float* __restrict__ h2,
                       float* acc2) {
    int e = blockIdx.x * blockDim.x + threadIdx.x;
    if (e >= E) return;
    int s = src[e];
    int d = dst[e];
    atomicAdd(&acc2[d], h2[s] * dinv[s] * dinv[d]);
}

// ---- sigmoid per node ------------------------------------------------------
__global__ void k_score(const float* __restrict__ b2, float* acc2) {
    int i = blockIdx.x * blockDim.x + threadIdx.x;
    if (i >= N) return;
    float v = acc2[i] + b2[0];
    acc2[i] = 1.0f / (1.0f + expf(-v));   // array now holds scores
}

// ---- gather per original edge: out[e] = scores[src[e]] ---------------------
__global__ void k_out(const int* __restrict__ src,
                      const float* __restrict__ scores,
                      float* __restrict__ out) {
    int e = blockIdx.x * blockDim.x + threadIdx.x;
    if (e >= E) return;
    out[e] = scores[src[e]];
}

extern "C" void kernel_launch(void* const* d_in, const int* in_sizes, int n_in,
                              void* d_out, int out_size, void* d_ws, size_t ws_size,
                              hipStream_t stream) {
    const float* x  = (const float*)d_in[0];   // [N,2]
    const float* W1 = (const float*)d_in[1];   // [2,16] row-major
    const float* b1 = (const float*)d_in[2];   // [16]
    const float* W2 = (const float*)d_in[3];   // [16,1]
    const float* b2 = (const float*)d_in[4];   // [1]
    const int*   ei = (const int*)d_in[5];     // [2,E]
    const int* src = ei;
    const int* dst = ei + E;

    float* ws   = (float*)d_ws;
    float* deg  = ws;                          // [N] -> becomes dinv
    float* ax   = deg + N;                     // [N*2]
    float* h2   = ax + (size_t)N * 2;          // [N]
    float* acc2 = h2 + N;                      // [N] -> becomes scores
    float* out  = (float*)d_out;               // [E]

    dim3 blk(256);
    k_deg_init <<<N / 256,        blk, 0, stream>>>(deg);
    k_deg_edges<<<E / 256,        blk, 0, stream>>>(dst, deg);
    k_dinv_seed<<<N / 256,        blk, 0, stream>>>(x, deg, ax);
    k_aggx     <<<(E / 256) * 2,  blk, 0, stream>>>(src, dst, deg, x, ax);
    k_node2    <<<N / 256,        blk, 0, stream>>>(ax, W1, b1, W2, deg, h2, acc2);
    k_agg2     <<<E / 256,        blk, 0, stream>>>(src, dst, deg, h2, acc2);
    k_score    <<<N / 256,        blk, 0, stream>>>(b2, acc2);
    k_out      <<<E / 256,        blk, 0, stream>>>(src, acc2, out);
}